// Round 5
// baseline (709.116 us; speedup 1.0000x reference)
//
#include <hip/hip_runtime.h>

#define BATCH   8
#define HH      512
#define WW      512
#define IMGPIX  (HH * WW)          // 262144 = 1<<18
#define NPIX    (BATCH * IMGPIX)   // 2097152
#define NWORDS  (NPIX / 64)        // 32768 packed words
#define KFAC    60.0f
#define WPR     8                  // 64-bit words per 512-px row
#define FPSCALE 262144.0           // 2^18 fixed-point scale for i64 reduction

// ---- skeleton partitioning ----
#define BPI     8                  // blocks per image
#define GZ      8                  // ghost rows each side == substeps per chunk
#define OWN     64                 // owned rows per block (HH / BPI)
#define ROWS    (OWN + 2 * GZ)     // 80 LDS rows
#define STHREADS (ROWS * WPR)      // 640 threads (10 waves)
#define LROW    9                  // padded LDS row stride in words
#define MAXC    64                 // max chunks (= 256 pairs cap)

typedef unsigned long long u64;
typedef unsigned int u32;

// ---------------- kernel 1: CE loss + packed mask + zero accumulators/barriers ----------------
__global__ void prep_kernel(const float* __restrict__ pred, const int* __restrict__ target,
                            float* __restrict__ L, u64* __restrict__ xp,
                            u64* __restrict__ acc64, u32* __restrict__ ticket,
                            u32* __restrict__ barchg) {
    int i = blockIdx.x * blockDim.x + threadIdx.x;
    if (i == 0) { acc64[0] = 0ULL; ticket[0] = 0u; }
    if (blockIdx.x == 0 && threadIdx.x < (BATCH + BATCH * MAXC))
        barchg[threadIdx.x] = 0u;            // bar[8] ++ chg[8*64], contiguous
    if (i >= NPIX) return;
    int b = i >> 18;
    int hw = i & (IMGPIX - 1);
    float p0 = pred[((size_t)(2 * b) << 18) + hw];
    float p1 = pred[((size_t)(2 * b + 1) << 18) + hw];
    float m = fmaxf(p0, p1);
    float lse = m + logf(expf(p0 - m) + expf(p1 - m));
    int t = target[i];
    L[i] = lse - (t ? p1 : p0);            // -log_softmax[target]
    u64 word = __ballot(p1 > p0);          // 64 consecutive pixels per wave
    if ((threadIdx.x & 63) == 0) xp[i >> 6] = word;
}

// ---------------- bit-sliced helpers ----------------
#define FA(a,b,c,s,cy) { u64 _x = (a)^(b); (s) = _x^(c); (cy) = ((a)&(b)) | ((c)&_x); }
#define HA(a,b,s,cy)   { (s) = (a)^(b); (cy) = (a)&(b); }

// Zhang-Suen delete test on one 64-px word given the 3x3 word neighborhood.
__device__ __forceinline__ u64 zs_word(int first,
    u64 Up, u64 Uc, u64 Un, u64 Mp, u64 Mc, u64 Mn, u64 Dp, u64 Dc, u64 Dn,
    u64* delp)
{
    if (Mc == 0ULL) { *delp = 0ULL; return 0ULL; }   // nothing deletable
    u64 P2 = Uc, P6 = Dc;
    u64 P3 = (Uc >> 1) | (Un << 63);
    u64 P4 = (Mc >> 1) | (Mn << 63);
    u64 P5 = (Dc >> 1) | (Dn << 63);
    u64 P9 = (Uc << 1) | (Up >> 63);
    u64 P8 = (Mc << 1) | (Mp >> 63);
    u64 P7 = (Dc << 1) | (Dp >> 63);

    u64 sa,ca, sb,cb, sc,cc, b0,cd, sd,ce, b1,cf, b2,b3;
    FA(P2,P3,P4, sa,ca);
    FA(P5,P6,P7, sb,cb);
    FA(P8,P9,sa, sc,cc);
    HA(sb,sc,    b0,cd);
    FA(ca,cb,cc, sd,ce);
    HA(sd,cd,    b1,cf);
    HA(ce,cf,    b2,b3);
    u64 ge2 = b1 | b2 | b3;
    u64 le6 = ~(b3 | (b0 & b1 & b2));

    u64 e, seen, two = 0;
    seen = (~P2) & P3;
    e = (~P3) & P4; two |= seen & e; seen |= e;
    e = (~P4) & P5; two |= seen & e; seen |= e;
    e = (~P5) & P6; two |= seen & e; seen |= e;
    e = (~P6) & P7; two |= seen & e; seen |= e;
    e = (~P7) & P8; two |= seen & e; seen |= e;
    e = (~P8) & P9; two |= seen & e; seen |= e;
    e = (~P9) & P2; two |= seen & e; seen |= e;
    u64 A1 = seen & ~two;

    u64 c34;
    if (first) { u64 t = P4 & P6; c34 = t & (P2 | P8); }
    else       { u64 t = P2 & P8; c34 = t & (P4 | P6); }

    u64 del = Mc & ge2 & le6 & A1 & ~c34;
    *delp = del;
    return Mc ^ del;
}

// ---------------- kernel 2: ghost-zone multi-block skeletonize + endpoints ----------------
// grid = BATCH*BPI blocks, 640 threads. Launched cooperatively (co-residency for spin barrier).
__global__ __launch_bounds__(STHREADS)
void skel_kernel(const u64* __restrict__ xp, u64* __restrict__ xs,
                 u64* __restrict__ eg, u32* __restrict__ bar, u32* __restrict__ chg)
{
    __shared__ u64 lds[2][ROWS * LROW];    // 11,520 B
    __shared__ u32 sh_ch;
    const int blk  = blockIdx.x;
    const int img  = blk / BPI;
    const int part = blk - img * BPI;
    const int t    = threadIdx.x;
    const int rL   = t >> 3;               // LDS row 0..79
    const int wc   = t & 7;                // word column 0..7
    const int gr0  = part * OWN - GZ;      // global row of LDS row 0
    const u64* src = xp + ((size_t)img << 12);

    {   // initial load (ghosts from xp; outside image -> 0, stays 0 by monotonicity)
        int gr = gr0 + rL;
        lds[0][rL * LROW + wc] = ((unsigned)gr < (unsigned)HH) ? src[gr * WPR + wc] : 0ULL;
        lds[1][rL * LROW + wc] = 0ULL;
    }
    __syncthreads();

    for (int chunk = 0; chunk < MAXC; ++chunk) {
        u32 mych = 0;
        #pragma unroll
        for (int s = 0; s < GZ; ++s) {               // 8 substeps = 4 ZS pairs
            const u64* B = lds[s & 1];
            int base = rL * LROW + wc;
            u64 Mc = B[base];
            u64 Mp = wc       ? B[base - 1] : 0ULL;
            u64 Mn = (wc < 7) ? B[base + 1] : 0ULL;
            u64 Uc = 0, Up = 0, Un = 0, Dc = 0, Dp = 0, Dn = 0;
            if (rL > 0) {
                Uc = B[base - LROW];
                Up = wc       ? B[base - LROW - 1] : 0ULL;
                Un = (wc < 7) ? B[base - LROW + 1] : 0ULL;
            }
            if (rL < ROWS - 1) {
                Dc = B[base + LROW];
                Dp = wc       ? B[base + LROW - 1] : 0ULL;
                Dn = (wc < 7) ? B[base + LROW + 1] : 0ULL;
            }
            u64 del;
            u64 nw = zs_word((s & 1) == 0, Up, Uc, Un, Mp, Mc, Mn, Dp, Dc, Dn, &del);
            lds[(s & 1) ^ 1][base] = nw;
            if (del && rL >= GZ && rL < GZ + OWN) mych = 1;   // owned-row changes only
            __syncthreads();
        }
        // image state back in lds[0] (8 flips)
        u32 blockch = __syncthreads_or(mych);

        // write boundary owned rows (top GZ, bottom GZ) to xs[parity]
        u64* xsp = xs + (size_t)(chunk & 1) * NWORDS + ((size_t)img << 12);
        if (t < 2 * GZ * WPR) {                      // 128 threads
            int k = t >> 3, bwc = t & 7;
            int brL = (k < GZ) ? (GZ + k) : (OWN - GZ + k);   // rows 8..15, 64..71
            int gr = gr0 + brL;
            xsp[gr * WPR + bwc] = lds[0][brL * LROW + bwc];
        }
        if (t == 0) {
            if (blockch) atomicOr(&chg[img * MAXC + chunk], 1u);
            __threadfence();                          // publish xs writes + chg
            atomicAdd(&bar[img], 1u);
            u32 tgt = (u32)(BPI * (chunk + 1));
            while (__hip_atomic_load(&bar[img], __ATOMIC_ACQUIRE, __HIP_MEMORY_SCOPE_AGENT) < tgt)
                __builtin_amdgcn_s_sleep(8);
            sh_ch = chg[img * MAXC + chunk];
        }
        __syncthreads();
        u32 anych = sh_ch;
        // reload ghosts from neighbors' boundary rows
        if (t < 2 * GZ * WPR) {
            int k = t >> 3, bwc = t & 7;
            int grL = (k < GZ) ? k : (OWN + k);      // ghost rows 0..7, 72..79
            int gr = gr0 + grL;
            if ((unsigned)gr < (unsigned)HH)
                lds[0][grL * LROW + bwc] = xsp[gr * WPR + bwc];
        }
        __syncthreads();
        if (!anych) break;                           // whole image at fixpoint
    }

    // ---- endpoints E = skel & (exactly one 8-neighbor), owned rows only
    if (rL >= GZ && rL < GZ + OWN) {
        const u64* B = lds[0];
        int base = rL * LROW + wc;
        u64 Mc = B[base];
        u64 Mp = wc       ? B[base - 1] : 0ULL;
        u64 Mn = (wc < 7) ? B[base + 1] : 0ULL;
        u64 Uc = B[base - LROW];
        u64 Up = wc       ? B[base - LROW - 1] : 0ULL;
        u64 Un = (wc < 7) ? B[base - LROW + 1] : 0ULL;
        u64 Dc = B[base + LROW];
        u64 Dp = wc       ? B[base + LROW - 1] : 0ULL;
        u64 Dn = (wc < 7) ? B[base + LROW + 1] : 0ULL;
        u64 P2 = Uc, P6 = Dc;
        u64 P3 = (Uc >> 1) | (Un << 63);
        u64 P4 = (Mc >> 1) | (Mn << 63);
        u64 P5 = (Dc >> 1) | (Dn << 63);
        u64 P9 = (Uc << 1) | (Up >> 63);
        u64 P8 = (Mc << 1) | (Mp >> 63);
        u64 P7 = (Dc << 1) | (Dp >> 63);
        u64 e, seen, two = 0;
        seen = P2;
        e = P3; two |= seen & e; seen |= e;
        e = P4; two |= seen & e; seen |= e;
        e = P5; two |= seen & e; seen |= e;
        e = P6; two |= seen & e; seen |= e;
        e = P7; two |= seen & e; seen |= e;
        e = P8; two |= seen & e; seen |= e;
        e = P9; two |= seen & e; seen |= e;
        eg[((size_t)img << 12) + (size_t)(gr0 + rL) * WPR + wc] = Mc & seen & ~two;
    }
}

// ---------------- packed-count helpers ----------------
struct Planes { u64 p0, p1, p2, p3; };

__device__ __forceinline__ Planes vcount9(const u64 r[9]) {
    u64 s0,c0, s1,c1, s2,c2, p0,t0, t1,t2, p1,t3, p2,p3;
    FA(r[0],r[1],r[2], s0,c0);
    FA(r[3],r[4],r[5], s1,c1);
    FA(r[6],r[7],r[8], s2,c2);
    FA(s0,s1,s2, p0,t0);
    FA(c0,c1,c2, t1,t2);
    HA(t0,t1,    p1,t3);
    HA(t2,t3,    p2,p3);
    Planes P; P.p0 = p0; P.p1 = p1; P.p2 = p2; P.p3 = p3; return P;
}

__device__ __forceinline__ u64 spread8(u64 bb) {
    u64 s = (bb * 0x0101010101010101ULL) & 0x8040201008040201ULL;
    return ((s + 0x7f7f7f7f7f7f7f7fULL) >> 7) & 0x0101010101010101ULL;
}

__device__ __forceinline__ u64 vbytes(const Planes& P, int g) {
    int s = 8 * g;
    return  spread8((P.p0 >> s) & 0xFFULL)
         + (spread8((P.p1 >> s) & 0xFFULL) << 1)
         + (spread8((P.p2 >> s) & 0xFFULL) << 2)
         + (spread8((P.p3 >> s) & 0xFFULL) << 3);
}

// ---------------- kernel 3: dense weighted sum ----------------
__global__ __launch_bounds__(256)
void final_kernel(const float* __restrict__ L, const u64* __restrict__ eg,
                  u64* __restrict__ acc64, u32* __restrict__ ticket,
                  float* __restrict__ out) {
    __shared__ float sm[256];
    int wi = blockIdx.x * blockDim.x + threadIdx.x;   // word index, 32768 total
    int b  = wi >> 12;
    int h  = (wi >> 3) & (HH - 1);
    int wc = wi & 7;
    const u64* img = eg + ((size_t)b << 12);

    u64 rows[3][9];
    #pragma unroll
    for (int dh = -4; dh <= 4; ++dh) {
        int hh = h + dh;
        bool okh = (unsigned)hh < (unsigned)HH;
        const u64* rp = img + hh * WPR;
        rows[0][dh + 4] = (okh && wc > 0) ? rp[wc - 1] : 0ULL;
        rows[1][dh + 4] = okh             ? rp[wc]     : 0ULL;
        rows[2][dh + 4] = (okh && wc < 7) ? rp[wc + 1] : 0ULL;
    }
    Planes Pm = vcount9(rows[0]);
    Planes Pc = vcount9(rows[1]);
    Planes Pp = vcount9(rows[2]);

    u64 v[10];
    v[0] = vbytes(Pm, 7);
    #pragma unroll
    for (int g = 0; g < 8; ++g) v[g + 1] = vbytes(Pc, g);
    v[9] = vbytes(Pp, 0);

    const float4* Lr = (const float4*)(L + ((size_t)wi << 6));
    float acc = 0.0f;
    #pragma unroll
    for (int g = 0; g < 8; ++g) {
        u64 a = v[g + 1], lo = v[g], hi = v[g + 2];
        u64 n = a;
        #pragma unroll
        for (int d = 1; d <= 4; ++d) {
            n += (a >> (8 * d)) | (hi << (64 - 8 * d));
            n += (a << (8 * d)) | (lo >> (64 - 8 * d));
        }
        float4 f0 = Lr[2 * g], f1 = Lr[2 * g + 1];
        #pragma unroll
        for (int j = 0; j < 8; ++j) {
            int cnt = (int)((n >> (8 * j)) & 0xFFULL);
            float wgt = cnt ? (float)(60 * cnt) : 1.0f;
            float lv = (j < 4) ? ((j == 0) ? f0.x : (j == 1) ? f0.y : (j == 2) ? f0.z : f0.w)
                               : ((j == 4) ? f1.x : (j == 5) ? f1.y : (j == 6) ? f1.z : f1.w);
            acc += wgt * lv;
        }
    }

    sm[threadIdx.x] = acc;
    __syncthreads();
    for (int s = 128; s > 0; s >>= 1) {
        if (threadIdx.x < s) sm[threadIdx.x] += sm[threadIdx.x + s];
        __syncthreads();
    }
    if (threadIdx.x == 0) {
        u64 vfx = (u64)(long long)llrintf(sm[0] * (float)FPSCALE);
        atomicAdd(acc64, vfx);
        __threadfence();
        u32 t = atomicAdd(ticket, 1u);
        if (t == (u32)(gridDim.x - 1)) {
            __threadfence();
            u64 total = __hip_atomic_load(acc64, __ATOMIC_RELAXED, __HIP_MEMORY_SCOPE_AGENT);
            out[0] = (float)((double)(long long)total / (FPSCALE * (double)NPIX));
        }
    }
}

extern "C" void kernel_launch(void* const* d_in, const int* in_sizes, int n_in,
                              void* d_out, int out_size, void* d_ws, size_t ws_size,
                              hipStream_t stream) {
    const float* pred = (const float*)d_in[0];
    const int* target = (const int*)d_in[1];
    float* out = (float*)d_out;
    char* ws = (char*)d_ws;

    // ws layout (bytes):
    //   [0,        8388608)  L       float[NPIX]
    //   [8388608,  8650752)  xp      u64[NWORDS]    packed mask
    //   [8650752,  8912896)  eg      u64[NWORDS]    packed endpoints
    //   [8912896,  9437184)  xs      u64[2*NWORDS]  parity-buffered halo exchange
    //   [9437184,  9437192)  acc64   u64
    //   [9437192,  9437196)  ticket  u32
    //   [9437196,  9437228)  bar     u32[8]
    //   [9437228,  9439276)  chg     u32[8*64]
    float* L    = (float*)(ws);
    u64* xp     = (u64*)(ws + 8388608);
    u64* eg     = (u64*)(ws + 8650752);
    u64* xs     = (u64*)(ws + 8912896);
    u64* acc64  = (u64*)(ws + 9437184);
    u32* ticket = (u32*)(ws + 9437192);
    u32* bar    = (u32*)(ws + 9437196);
    u32* chg    = (u32*)(ws + 9437228);

    prep_kernel<<<dim3(NPIX / 256), dim3(256), 0, stream>>>(pred, target, L, xp, acc64, ticket, bar);

    {
        void* args[] = { (void*)&xp, (void*)&xs, (void*)&eg, (void*)&bar, (void*)&chg };
        hipLaunchCooperativeKernel((void*)skel_kernel, dim3(BATCH * BPI), dim3(STHREADS),
                                   args, 0, stream);
    }

    final_kernel<<<dim3(NWORDS / 256), dim3(256), 0, stream>>>(L, eg, acc64, ticket, out);
}

// Round 6
// 70.135 us; speedup vs baseline: 10.1107x; 10.1107x over previous
//
#include <hip/hip_runtime.h>

#define BATCH   8
#define HH      512
#define WW      512
#define IMGPIX  (HH * WW)          // 262144 = 1<<18
#define NPIX    (BATCH * IMGPIX)   // 2097152
#define NWORDS  (NPIX / 64)        // 32768 packed words
#define KFAC    60.0f
#define WPR     8                  // 64-bit words per 512-px row
#define FPSCALE 262144.0           // 2^18 fixed-point scale for i64 reduction

// ---- skeleton partitioning ----
#define BPI     8                  // blocks per image
#define GZ      8                  // ghost rows each side == substeps per chunk
#define OWN     64                 // owned rows per block (HH / BPI)
#define ROWS    (OWN + 2 * GZ)     // 80 LDS rows
#define STHREADS (ROWS * WPR)      // 640 threads (10 waves)
#define LROW    9                  // padded LDS row stride in words
#define MAXC    64                 // max chunks (= 256 pairs cap)
#define NBARCHG (BATCH + BATCH * MAXC)   // bar[8] ++ chg[8*64] = 520 words

typedef unsigned long long u64;
typedef unsigned int u32;

// ---------------- kernel 1: CE loss + packed mask + zero accumulators/barriers ----------------
__global__ void prep_kernel(const float* __restrict__ pred, const int* __restrict__ target,
                            float* __restrict__ L, u64* __restrict__ xp,
                            u64* __restrict__ acc64, u32* __restrict__ ticket,
                            u32* __restrict__ barchg) {
    int i = blockIdx.x * blockDim.x + threadIdx.x;
    if (i == 0) { acc64[0] = 0ULL; ticket[0] = 0u; }
    if (i < NBARCHG) barchg[i] = 0u;       // GLOBAL index: covers all 520 words (R4 bug fix)
    if (i >= NPIX) return;
    int b = i >> 18;
    int hw = i & (IMGPIX - 1);
    float p0 = pred[((size_t)(2 * b) << 18) + hw];
    float p1 = pred[((size_t)(2 * b + 1) << 18) + hw];
    float m = fmaxf(p0, p1);
    float lse = m + logf(expf(p0 - m) + expf(p1 - m));
    int t = target[i];
    L[i] = lse - (t ? p1 : p0);            // -log_softmax[target]
    u64 word = __ballot(p1 > p0);          // 64 consecutive pixels per wave
    if ((threadIdx.x & 63) == 0) xp[i >> 6] = word;
}

// ---------------- bit-sliced helpers ----------------
#define FA(a,b,c,s,cy) { u64 _x = (a)^(b); (s) = _x^(c); (cy) = ((a)&(b)) | ((c)&_x); }
#define HA(a,b,s,cy)   { (s) = (a)^(b); (cy) = (a)&(b); }

// Zhang-Suen delete test on one 64-px word given the 3x3 word neighborhood.
__device__ __forceinline__ u64 zs_word(int first,
    u64 Up, u64 Uc, u64 Un, u64 Mp, u64 Mc, u64 Mn, u64 Dp, u64 Dc, u64 Dn,
    u64* delp)
{
    if (Mc == 0ULL) { *delp = 0ULL; return 0ULL; }   // nothing deletable
    u64 P2 = Uc, P6 = Dc;
    u64 P3 = (Uc >> 1) | (Un << 63);
    u64 P4 = (Mc >> 1) | (Mn << 63);
    u64 P5 = (Dc >> 1) | (Dn << 63);
    u64 P9 = (Uc << 1) | (Up >> 63);
    u64 P8 = (Mc << 1) | (Mp >> 63);
    u64 P7 = (Dc << 1) | (Dp >> 63);

    u64 sa,ca, sb,cb, sc,cc, b0,cd, sd,ce, b1,cf, b2,b3;
    FA(P2,P3,P4, sa,ca);
    FA(P5,P6,P7, sb,cb);
    FA(P8,P9,sa, sc,cc);
    HA(sb,sc,    b0,cd);
    FA(ca,cb,cc, sd,ce);
    HA(sd,cd,    b1,cf);
    HA(ce,cf,    b2,b3);
    u64 ge2 = b1 | b2 | b3;
    u64 le6 = ~(b3 | (b0 & b1 & b2));

    u64 e, seen, two = 0;
    seen = (~P2) & P3;
    e = (~P3) & P4; two |= seen & e; seen |= e;
    e = (~P4) & P5; two |= seen & e; seen |= e;
    e = (~P5) & P6; two |= seen & e; seen |= e;
    e = (~P6) & P7; two |= seen & e; seen |= e;
    e = (~P7) & P8; two |= seen & e; seen |= e;
    e = (~P8) & P9; two |= seen & e; seen |= e;
    e = (~P9) & P2; two |= seen & e; seen |= e;
    u64 A1 = seen & ~two;

    u64 c34;
    if (first) { u64 t = P4 & P6; c34 = t & (P2 | P8); }
    else       { u64 t = P2 & P8; c34 = t & (P4 | P6); }

    u64 del = Mc & ge2 & le6 & A1 & ~c34;
    *delp = del;
    return Mc ^ del;
}

// ---------------- kernel 2: ghost-zone multi-block skeletonize + endpoints ----------------
// grid = BATCH*BPI blocks, 640 threads. Launched cooperatively (co-residency for spin barrier).
__global__ __launch_bounds__(STHREADS)
void skel_kernel(const u64* __restrict__ xp, u64* __restrict__ xs,
                 u64* __restrict__ eg, u32* __restrict__ bar, u32* __restrict__ chg)
{
    __shared__ u64 lds[2][ROWS * LROW];    // 11,520 B
    __shared__ u32 sh_ch;
    const int blk  = blockIdx.x;
    const int img  = blk / BPI;
    const int part = blk - img * BPI;
    const int t    = threadIdx.x;
    const int rL   = t >> 3;               // LDS row 0..79
    const int wc   = t & 7;                // word column 0..7
    const int gr0  = part * OWN - GZ;      // global row of LDS row 0
    const u64* src = xp + ((size_t)img << 12);

    {   // initial load (ghosts from xp; outside image -> 0, stays 0 by monotonicity)
        int gr = gr0 + rL;
        lds[0][rL * LROW + wc] = ((unsigned)gr < (unsigned)HH) ? src[gr * WPR + wc] : 0ULL;
        lds[1][rL * LROW + wc] = 0ULL;
    }
    __syncthreads();

    for (int chunk = 0; chunk < MAXC; ++chunk) {
        u32 mych = 0;
        #pragma unroll
        for (int s = 0; s < GZ; ++s) {               // 8 substeps = 4 ZS pairs
            const u64* B = lds[s & 1];
            int base = rL * LROW + wc;
            u64 Mc = B[base];
            u64 Mp = wc       ? B[base - 1] : 0ULL;
            u64 Mn = (wc < 7) ? B[base + 1] : 0ULL;
            u64 Uc = 0, Up = 0, Un = 0, Dc = 0, Dp = 0, Dn = 0;
            if (rL > 0) {
                Uc = B[base - LROW];
                Up = wc       ? B[base - LROW - 1] : 0ULL;
                Un = (wc < 7) ? B[base - LROW + 1] : 0ULL;
            }
            if (rL < ROWS - 1) {
                Dc = B[base + LROW];
                Dp = wc       ? B[base + LROW - 1] : 0ULL;
                Dn = (wc < 7) ? B[base + LROW + 1] : 0ULL;
            }
            u64 del;
            u64 nw = zs_word((s & 1) == 0, Up, Uc, Un, Mp, Mc, Mn, Dp, Dc, Dn, &del);
            lds[(s & 1) ^ 1][base] = nw;
            if (del && rL >= GZ && rL < GZ + OWN) mych = 1;   // owned-row changes only
            __syncthreads();
        }
        // image state back in lds[0] (8 flips)
        u32 blockch = __syncthreads_or(mych);

        // write boundary owned rows (top GZ, bottom GZ) to xs[parity]
        u64* xsp = xs + (size_t)(chunk & 1) * NWORDS + ((size_t)img << 12);
        if (t < 2 * GZ * WPR) {                      // 128 threads
            int k = t >> 3, bwc = t & 7;
            int brL = (k < GZ) ? (GZ + k) : (OWN - GZ + k);   // rows 8..15, 64..71
            int gr = gr0 + brL;
            xsp[gr * WPR + bwc] = lds[0][brL * LROW + bwc];
        }
        __syncthreads();   // R4 race fix: ALL boundary writes complete before signaling
        if (t == 0) {
            if (blockch) atomicOr(&chg[img * MAXC + chunk], 1u);
            __threadfence();                          // publish xs writes + chg
            atomicAdd(&bar[img], 1u);
            u32 tgt = (u32)(BPI * (chunk + 1));
            while (__hip_atomic_load(&bar[img], __ATOMIC_ACQUIRE, __HIP_MEMORY_SCOPE_AGENT) < tgt)
                __builtin_amdgcn_s_sleep(8);
            sh_ch = chg[img * MAXC + chunk];
        }
        __syncthreads();
        u32 anych = sh_ch;
        // reload ghosts from neighbors' boundary rows
        if (t < 2 * GZ * WPR) {
            int k = t >> 3, bwc = t & 7;
            int grL = (k < GZ) ? k : (OWN + k);      // ghost rows 0..7, 72..79
            int gr = gr0 + grL;
            if ((unsigned)gr < (unsigned)HH)
                lds[0][grL * LROW + bwc] = xsp[gr * WPR + bwc];
        }
        __syncthreads();
        if (!anych) break;                           // whole image at fixpoint
    }

    // ---- endpoints E = skel & (exactly one 8-neighbor), owned rows only
    if (rL >= GZ && rL < GZ + OWN) {
        const u64* B = lds[0];
        int base = rL * LROW + wc;
        u64 Mc = B[base];
        u64 Mp = wc       ? B[base - 1] : 0ULL;
        u64 Mn = (wc < 7) ? B[base + 1] : 0ULL;
        u64 Uc = B[base - LROW];
        u64 Up = wc       ? B[base - LROW - 1] : 0ULL;
        u64 Un = (wc < 7) ? B[base - LROW + 1] : 0ULL;
        u64 Dc = B[base + LROW];
        u64 Dp = wc       ? B[base + LROW - 1] : 0ULL;
        u64 Dn = (wc < 7) ? B[base + LROW + 1] : 0ULL;
        u64 P2 = Uc, P6 = Dc;
        u64 P3 = (Uc >> 1) | (Un << 63);
        u64 P4 = (Mc >> 1) | (Mn << 63);
        u64 P5 = (Dc >> 1) | (Dn << 63);
        u64 P9 = (Uc << 1) | (Up >> 63);
        u64 P8 = (Mc << 1) | (Mp >> 63);
        u64 P7 = (Dc << 1) | (Dp >> 63);
        u64 e, seen, two = 0;
        seen = P2;
        e = P3; two |= seen & e; seen |= e;
        e = P4; two |= seen & e; seen |= e;
        e = P5; two |= seen & e; seen |= e;
        e = P6; two |= seen & e; seen |= e;
        e = P7; two |= seen & e; seen |= e;
        e = P8; two |= seen & e; seen |= e;
        e = P9; two |= seen & e; seen |= e;
        eg[((size_t)img << 12) + (size_t)(gr0 + rL) * WPR + wc] = Mc & seen & ~two;
    }
}

// ---------------- packed-count helpers ----------------
struct Planes { u64 p0, p1, p2, p3; };

__device__ __forceinline__ Planes vcount9(const u64 r[9]) {
    u64 s0,c0, s1,c1, s2,c2, p0,t0, t1,t2, p1,t3, p2,p3;
    FA(r[0],r[1],r[2], s0,c0);
    FA(r[3],r[4],r[5], s1,c1);
    FA(r[6],r[7],r[8], s2,c2);
    FA(s0,s1,s2, p0,t0);
    FA(c0,c1,c2, t1,t2);
    HA(t0,t1,    p1,t3);
    HA(t2,t3,    p2,p3);
    Planes P; P.p0 = p0; P.p1 = p1; P.p2 = p2; P.p3 = p3; return P;
}

__device__ __forceinline__ u64 spread8(u64 bb) {
    u64 s = (bb * 0x0101010101010101ULL) & 0x8040201008040201ULL;
    return ((s + 0x7f7f7f7f7f7f7f7fULL) >> 7) & 0x0101010101010101ULL;
}

__device__ __forceinline__ u64 vbytes(const Planes& P, int g) {
    int s = 8 * g;
    return  spread8((P.p0 >> s) & 0xFFULL)
         + (spread8((P.p1 >> s) & 0xFFULL) << 1)
         + (spread8((P.p2 >> s) & 0xFFULL) << 2)
         + (spread8((P.p3 >> s) & 0xFFULL) << 3);
}

// ---------------- kernel 3: dense weighted sum ----------------
__global__ __launch_bounds__(256)
void final_kernel(const float* __restrict__ L, const u64* __restrict__ eg,
                  u64* __restrict__ acc64, u32* __restrict__ ticket,
                  float* __restrict__ out) {
    __shared__ float sm[256];
    int wi = blockIdx.x * blockDim.x + threadIdx.x;   // word index, 32768 total
    int b  = wi >> 12;
    int h  = (wi >> 3) & (HH - 1);
    int wc = wi & 7;
    const u64* img = eg + ((size_t)b << 12);

    u64 rows[3][9];
    #pragma unroll
    for (int dh = -4; dh <= 4; ++dh) {
        int hh = h + dh;
        bool okh = (unsigned)hh < (unsigned)HH;
        const u64* rp = img + hh * WPR;
        rows[0][dh + 4] = (okh && wc > 0) ? rp[wc - 1] : 0ULL;
        rows[1][dh + 4] = okh             ? rp[wc]     : 0ULL;
        rows[2][dh + 4] = (okh && wc < 7) ? rp[wc + 1] : 0ULL;
    }
    Planes Pm = vcount9(rows[0]);
    Planes Pc = vcount9(rows[1]);
    Planes Pp = vcount9(rows[2]);

    u64 v[10];
    v[0] = vbytes(Pm, 7);
    #pragma unroll
    for (int g = 0; g < 8; ++g) v[g + 1] = vbytes(Pc, g);
    v[9] = vbytes(Pp, 0);

    const float4* Lr = (const float4*)(L + ((size_t)wi << 6));
    float acc = 0.0f;
    #pragma unroll
    for (int g = 0; g < 8; ++g) {
        u64 a = v[g + 1], lo = v[g], hi = v[g + 2];
        u64 n = a;
        #pragma unroll
        for (int d = 1; d <= 4; ++d) {
            n += (a >> (8 * d)) | (hi << (64 - 8 * d));
            n += (a << (8 * d)) | (lo >> (64 - 8 * d));
        }
        float4 f0 = Lr[2 * g], f1 = Lr[2 * g + 1];
        #pragma unroll
        for (int j = 0; j < 8; ++j) {
            int cnt = (int)((n >> (8 * j)) & 0xFFULL);
            float wgt = cnt ? (float)(60 * cnt) : 1.0f;
            float lv = (j < 4) ? ((j == 0) ? f0.x : (j == 1) ? f0.y : (j == 2) ? f0.z : f0.w)
                               : ((j == 4) ? f1.x : (j == 5) ? f1.y : (j == 6) ? f1.z : f1.w);
            acc += wgt * lv;
        }
    }

    sm[threadIdx.x] = acc;
    __syncthreads();
    for (int s = 128; s > 0; s >>= 1) {
        if (threadIdx.x < s) sm[threadIdx.x] += sm[threadIdx.x + s];
        __syncthreads();
    }
    if (threadIdx.x == 0) {
        u64 vfx = (u64)(long long)llrintf(sm[0] * (float)FPSCALE);
        atomicAdd(acc64, vfx);
        __threadfence();
        u32 t = atomicAdd(ticket, 1u);
        if (t == (u32)(gridDim.x - 1)) {
            __threadfence();
            u64 total = __hip_atomic_load(acc64, __ATOMIC_RELAXED, __HIP_MEMORY_SCOPE_AGENT);
            out[0] = (float)((double)(long long)total / (FPSCALE * (double)NPIX));
        }
    }
}

extern "C" void kernel_launch(void* const* d_in, const int* in_sizes, int n_in,
                              void* d_out, int out_size, void* d_ws, size_t ws_size,
                              hipStream_t stream) {
    const float* pred = (const float*)d_in[0];
    const int* target = (const int*)d_in[1];
    float* out = (float*)d_out;
    char* ws = (char*)d_ws;

    // ws layout (bytes):
    //   [0,        8388608)  L       float[NPIX]
    //   [8388608,  8650752)  xp      u64[NWORDS]    packed mask
    //   [8650752,  8912896)  eg      u64[NWORDS]    packed endpoints
    //   [8912896,  9437184)  xs      u64[2*NWORDS]  parity-buffered halo exchange
    //   [9437184,  9437192)  acc64   u64
    //   [9437192,  9437196)  ticket  u32
    //   [9437196,  9437228)  bar     u32[8]
    //   [9437228,  9439276)  chg     u32[8*64]
    float* L    = (float*)(ws);
    u64* xp     = (u64*)(ws + 8388608);
    u64* eg     = (u64*)(ws + 8650752);
    u64* xs     = (u64*)(ws + 8912896);
    u64* acc64  = (u64*)(ws + 9437184);
    u32* ticket = (u32*)(ws + 9437192);
    u32* bar    = (u32*)(ws + 9437196);
    u32* chg    = (u32*)(ws + 9437228);

    prep_kernel<<<dim3(NPIX / 256), dim3(256), 0, stream>>>(pred, target, L, xp, acc64, ticket, bar);

    {
        void* args[] = { (void*)&xp, (void*)&xs, (void*)&eg, (void*)&bar, (void*)&chg };
        hipLaunchCooperativeKernel((void*)skel_kernel, dim3(BATCH * BPI), dim3(STHREADS),
                                   args, 0, stream);
    }

    final_kernel<<<dim3(NWORDS / 256), dim3(256), 0, stream>>>(L, eg, acc64, ticket, out);
}